// Round 6
// baseline (169.346 us; speedup 1.0000x reference)
//
#include <hip/hip_runtime.h>
#include <hip/hip_bf16.h>

#define S_LEN 4096
#define HID   768
#define NH    12
#define HD    64

typedef __attribute__((ext_vector_type(8))) __bf16 bf16x8;
typedef __attribute__((ext_vector_type(4))) float  f32x4;

// round-to-nearest-even fp32 -> bf16
__device__ __forceinline__ unsigned short f2bf(float f) {
  union { float f; unsigned u; } v; v.f = f;
  unsigned r = v.u + 0x7fffu + ((v.u >> 16) & 1u);
  return (unsigned short)(r >> 16);
}

// truncating pack of two fp32 into [bf16(hi) | bf16(lo)] — single v_perm_b32.
__device__ __forceinline__ unsigned pktr(float lo, float hi) {
  union { float f; unsigned u; } a, b; a.f = lo; b.f = hi;
  return __builtin_amdgcn_perm(b.u, a.u, 0x07060302u);
}

// async global->LDS DMA, 16B/lane. LDS dest = wave-uniform base + lane*16.
#define GLL(gp, lp) __builtin_amdgcn_global_load_lds(                      \
    (__attribute__((address_space(1))) void*)(gp),                         \
    (__attribute__((address_space(3))) void*)(lp), 16, 0, 0)

// ---------------------------------------------------------------------------
// Prep: X->bf16 | W->Wt bf16 transposed.
// ---------------------------------------------------------------------------
__global__ __launch_bounds__(256) void prep(
    const float* __restrict__ X,
    const float* __restrict__ Wq, const float* __restrict__ Wk, const float* __restrict__ Wv,
    unsigned short* __restrict__ Xb, unsigned short* __restrict__ Wt)
{
  const int b = blockIdx.x, tid = threadIdx.x;
  __shared__ unsigned short T[64][72];

  if (b < 3072) {                      // X fp32 -> bf16
    const int i = b * 256 + tid;
    const float4 v = ((const float4*)X)[i];
    ushort4 o;
    o.x = f2bf(v.x); o.y = f2bf(v.y); o.z = f2bf(v.z); o.w = f2bf(v.w);
    ((ushort4*)Xb)[i] = o;
  } else {                             // W [k][n] -> Wt [n][k] bf16, 64x64 tiles
    const int t = b - 3072;
    const int z = t / 144, rem = t % 144;
    const int k0 = (rem / 12) * 64, n0 = (rem % 12) * 64;
    const float* W = (z == 0) ? Wq : (z == 1) ? Wk : Wv;
    unsigned short* Od = Wt + (size_t)z * HID * HID;
    #pragma unroll
    for (int i = tid; i < 512; i += 256) {
      const int kr = i >> 3, c8 = (i & 7) * 8;
      const float4 a = *(const float4*)&W[(size_t)(k0 + kr) * HID + n0 + c8];
      const float4 bb = *(const float4*)&W[(size_t)(k0 + kr) * HID + n0 + c8 + 4];
      T[kr][c8 + 0] = f2bf(a.x);  T[kr][c8 + 1] = f2bf(a.y);
      T[kr][c8 + 2] = f2bf(a.z);  T[kr][c8 + 3] = f2bf(a.w);
      T[kr][c8 + 4] = f2bf(bb.x); T[kr][c8 + 5] = f2bf(bb.y);
      T[kr][c8 + 6] = f2bf(bb.z); T[kr][c8 + 7] = f2bf(bb.w);
    }
    __syncthreads();
    #pragma unroll
    for (int i = tid; i < 512; i += 256) {
      const int nr = i >> 3, c8 = (i & 7) * 8;
      ushort4 lo, hi;
      lo.x = T[c8 + 0][nr]; lo.y = T[c8 + 1][nr]; lo.z = T[c8 + 2][nr]; lo.w = T[c8 + 3][nr];
      hi.x = T[c8 + 4][nr]; hi.y = T[c8 + 5][nr]; hi.z = T[c8 + 6][nr]; hi.w = T[c8 + 7][nr];
      ushort4* dst = (ushort4*)&Od[(size_t)(n0 + nr) * HID + k0 + c8];
      dst[0] = lo; dst[1] = hi;
    }
  }
}

// ---------------------------------------------------------------------------
// Kernel 1: QKV projection, attn-style loop: 256x64 tile, 8 waves x 32 rows,
// DOUBLE-buffered 80 KB LDS, ONE barrier per K-slab (12 vs 24 before).
// 2 WGs/CU resident (LDS) -> 16 waves/CU. GLL staging, pre-swizzled source
// (invariant LDS[r][x] = G[r][x ^ ((r&7)*8)]). Grid (12 h, 16 mt, 3 z).
// Q pre-scaled by 0.125*log2(e). V written [h][d][s_p]; within-32 key perm
// is wave-invariant (s mod 32 = mt*16+4g+r) -> col = wave*32 + g*8 + r + mt*4.
// ---------------------------------------------------------------------------
__global__ __launch_bounds__(512, 4) void qkv_proj(
    const unsigned short* __restrict__ Xb, const unsigned short* __restrict__ Wt,
    const float* __restrict__ bq, const float* __restrict__ bk, const float* __restrict__ bv,
    unsigned short* __restrict__ Qo, unsigned short* __restrict__ Ko, unsigned short* __restrict__ Vo)
{
  const int z = blockIdx.z;
  const unsigned short* W = Wt + (size_t)z * HID * HID;   // [n][k]
  const float* bias = (z == 0) ? bq : (z == 1) ? bk : bv;
  unsigned short* Out = (z == 0) ? Qo : (z == 1) ? Ko : Vo;

  const int tid  = threadIdx.x;
  const int wave = tid >> 6;           // 0..7
  const int lane = tid & 63;
  const int g = lane >> 4, c = lane & 15;
  const int h  = blockIdx.x;
  const int n0 = h * 64;
  const int m0 = blockIdx.y * 256;

  __shared__ unsigned short Xl[2][16384];   // [256][64] swizzled, dbuf
  __shared__ unsigned short Wl[2][4096];    // [64][64]  swizzled, dbuf

  // staging: pre-swizzled source column (involution within 8-row groups)
  const int sr  = lane >> 3;
  const int scb = ((lane & 7) ^ sr) * 8;
  // X: wave w issue i in {0..3} covers rows wave*32 + i*8 + sr
  const unsigned short* xG = &Xb[(size_t)(m0 + wave * 32 + sr) * HID + scb];
  // W: wave w covers rows wave*8 + sr
  const unsigned short* wG = &W[(size_t)(n0 + wave * 8 + sr) * HID + scb];

  const int swz = (c & 7) * 8;
  unsigned aRi[2][2], bRi[4][2];
  #pragma unroll
  for (int mt = 0; mt < 2; ++mt)
    #pragma unroll
    for (int kk = 0; kk < 2; ++kk)
      aRi[mt][kk] = (wave * 32 + mt * 16 + c) * 64 + ((kk * 32 + g * 8) ^ swz);
  #pragma unroll
  for (int nt = 0; nt < 4; ++nt)
    #pragma unroll
    for (int kk = 0; kk < 2; ++kk)
      bRi[nt][kk] = (nt * 16 + c) * 64 + ((kk * 32 + g * 8) ^ swz);

  f32x4 acc[2][4];
  #pragma unroll
  for (int mt = 0; mt < 2; ++mt)
    #pragma unroll
    for (int nt = 0; nt < 4; ++nt) acc[mt][nt] = (f32x4){0.f, 0.f, 0.f, 0.f};

  // prologue: slab 0 -> buf 0
  #pragma unroll
  for (int i = 0; i < 4; ++i) GLL(xG + (size_t)i * 8 * HID, &Xl[0][(wave * 4 + i) * 512]);
  GLL(wG, &Wl[0][wave * 512]);
  xG += 64; wG += 64;

  const int NSLAB = HID / 64;   // 12
  for (int ks = 0; ks < NSLAB; ++ks) {
    __syncthreads();                 // drains GLLs into buf[cur]; frees buf[cur^1]
    const int cur = ks & 1;
    if (ks + 1 < NSLAB) {            // async-prefetch next slab into other buffer
      const int nxt = cur ^ 1;
      #pragma unroll
      for (int i = 0; i < 4; ++i) GLL(xG + (size_t)i * 8 * HID, &Xl[nxt][(wave * 4 + i) * 512]);
      GLL(wG, &Wl[nxt][wave * 512]);
      xG += 64; wG += 64;
    }

    const bf16x8 a00 = *(const bf16x8*)&Xl[cur][aRi[0][0]];
    const bf16x8 a01 = *(const bf16x8*)&Xl[cur][aRi[0][1]];
    const bf16x8 a10 = *(const bf16x8*)&Xl[cur][aRi[1][0]];
    const bf16x8 a11 = *(const bf16x8*)&Xl[cur][aRi[1][1]];
    __builtin_amdgcn_s_setprio(1);
    #pragma unroll
    for (int nt = 0; nt < 4; ++nt) {
      const bf16x8 b0 = *(const bf16x8*)&Wl[cur][bRi[nt][0]];
      const bf16x8 b1 = *(const bf16x8*)&Wl[cur][bRi[nt][1]];
      acc[0][nt] = __builtin_amdgcn_mfma_f32_16x16x32_bf16(a00, b0, acc[0][nt], 0, 0, 0);
      acc[0][nt] = __builtin_amdgcn_mfma_f32_16x16x32_bf16(a01, b1, acc[0][nt], 0, 0, 0);
      acc[1][nt] = __builtin_amdgcn_mfma_f32_16x16x32_bf16(a10, b0, acc[1][nt], 0, 0, 0);
      acc[1][nt] = __builtin_amdgcn_mfma_f32_16x16x32_bf16(a11, b1, acc[1][nt], 0, 0, 0);
    }
    __builtin_amdgcn_s_setprio(0);
  }

  // epilogue: restage through Xl[0] (swizzled) -> coalesced b128 stores.
  // Last loop iter read buf (NSLAB-1)&1 = 1; Xl[0]'s readers finished before
  // the final barrier, so writing Xl[0] here races with nothing.
  const float qsc = (z == 0) ? 0.1803368782f : 1.0f;   // 0.125 * log2(e)
  #pragma unroll
  for (int mt = 0; mt < 2; ++mt) {
    #pragma unroll
    for (int nt = 0; nt < 4; ++nt) {
      const float bv_ = bias[n0 + nt * 16 + c];
      #pragma unroll
      for (int r = 0; r < 4; ++r) {
        const unsigned short val = f2bf((acc[mt][nt][r] + bv_) * qsc);
        if (z == 2) {
          // V: Xl[0] as [64][256]: row=d, col = wave*32 + g*8 + r + mt*4
          const int d = nt * 16 + c;
          const int col = wave * 32 + g * 8 + r + mt * 4;
          Xl[0][d * 256 + (col ^ ((d & 7) * 8))] = val;
        } else {
          const int row = wave * 32 + mt * 16 + 4 * g + r;
          const int col = nt * 16 + c;
          Xl[0][row * 64 + (col ^ ((row & 7) * 8))] = val;
        }
      }
    }
  }
  __syncthreads();
  #pragma unroll
  for (int jj = 0; jj < 4; ++jj) {
    const int j = tid + 512 * jj;          // 2048 bf16x8 total
    if (z == 2) {
      const int d = j >> 5, c8 = (j & 31) * 8;
      const bf16x8 v = *(const bf16x8*)&Xl[0][d * 256 + (c8 ^ ((d & 7) * 8))];
      *(bf16x8*)&Out[((size_t)h * HD + d) * S_LEN + m0 + c8] = v;     // [h][d][s_p]
    } else {
      const int row = j >> 3, c8 = (j & 7) * 8;
      const bf16x8 v = *(const bf16x8*)&Xl[0][row * 64 + (c8 ^ ((row & 7) * 8))];
      *(bf16x8*)&Out[((size_t)h * S_LEN + m0 + row) * HD + c8] = v;   // [h][s][d]
    }
  }
}

// ---------------------------------------------------------------------------
// Kernel 2: attention — 8 waves x 32 q = 256 q/WG, 512 threads. Residency is
// pinned at ~2 WGs/CU for 32 KB LDS (R1/R2/R4/R5: occupancy == 2 WGs x
// waves-per-WG regardless of grid), so waves/WG is the only occupancy lever:
// 8 waves -> 16 waves/CU (was 8 best-case). Per-wave body identical to R1's
// proven 4wx32q code (64 VGPR). NSP=4 -> 768 WGs, NIT=16, XCD-pinned (h,sp),
// double-buffered GLL staging, plain-store partials.
// ---------------------------------------------------------------------------
template<int NSP>
__global__ __launch_bounds__(512, 4) void attn(
    const unsigned short* __restrict__ Q, const unsigned short* __restrict__ K,
    const unsigned short* __restrict__ Vp,   // [h][d][s_p]
    float* __restrict__ O, float* __restrict__ Opb, float* __restrict__ Lp)
{
  const int b   = blockIdx.x;          // 0 .. 16*NH*NSP-1
  const int xcd = b & 7;
  const int idx = b >> 3;
  const int pg  = idx >> 4;            // 0 .. NH*NSP/8 - 1
  const int qt  = idx & 15;            // 0..15 (256-q tiles)
  const int pair = xcd + 8 * pg;       // pinned per XCD
  const int h  = pair / NSP;
  const int sp = pair % NSP;

  const int tid  = threadIdx.x;
  const int wave = tid >> 6;           // 0..7
  const int lane = tid & 63;
  const int g = lane >> 4, c = lane & 15;
  const int q0 = qt * 256;
  const int k_base = sp * (S_LEN / NSP);
  const int NIT = (S_LEN / NSP) / 64;

  __shared__ unsigned short KB[2][4096];   // [key][d] swizzled
  __shared__ unsigned short VB[2][4096];   // [d][key_p] swizzled

  // Q B-frags (loop-invariant): each wave owns 32 q rows = 2 s-tiles
  bf16x8 aq[2][2];
  #pragma unroll
  for (int s = 0; s < 2; ++s) {
    const size_t qrow = (size_t)h * S_LEN + q0 + wave * 32 + s * 16 + c;
    aq[s][0] = *(const bf16x8*)&Q[qrow * HD + g * 8];
    aq[s][1] = *(const bf16x8*)&Q[qrow * HD + 32 + g * 8];
  }

  bf16x8 bones8;   // B column 0 = 1.0 -> C[:,0] = row sums
  {
    const unsigned short one_bf = (c == 0) ? 0x3F80u : 0u;
    #pragma unroll
    for (int j = 0; j < 8; ++j) ((unsigned short*)&bones8)[j] = one_bf;
  }

  const int swz = (c & 7) * 8;
  unsigned kRi[8];             // read offsets; identical pattern serves K and V
  #pragma unroll
  for (int mt = 0; mt < 4; ++mt) {
    kRi[2 * mt]     = (mt * 16 + c) * 64 + ((g * 8) ^ swz);
    kRi[2 * mt + 1] = (mt * 16 + c) * 64 + ((32 + g * 8) ^ swz);
  }

  // staging: 8 waves x 1 GLL each per tensor; wave w covers rows w*8 + sr
  const int sr  = lane >> 3;
  const int scb = ((lane & 7) ^ sr) * 8;
  const unsigned short* kG = &K[((size_t)h * S_LEN + k_base + wave * 8 + sr) * HD + scb];
  const unsigned short* vG = &Vp[((size_t)h * HD + wave * 8 + sr) * S_LEN + k_base + scb];

  // prologue: slab 0 into buffer 0
  GLL(kG, &KB[0][wave * 512]);
  GLL(vG, &VB[0][wave * 512]);
  kG += (size_t)64 * HD; vG += 64;

  f32x4 o[2][4];
  #pragma unroll
  for (int s = 0; s < 2; ++s)
    #pragma unroll
    for (int dt = 0; dt < 4; ++dt) o[s][dt] = (f32x4){0.f, 0.f, 0.f, 0.f};
  f32x4 lacc[2] = {{0.f,0.f,0.f,0.f},{0.f,0.f,0.f,0.f}};

  for (int kt = 0; kt < NIT; ++kt) {
    __syncthreads();                 // drains DMA into buf[cur]; frees buf[cur^1]
    const int cur = kt & 1;
    if (kt + 1 < NIT) {              // async-prefetch next slab into other buffer
      const int nxt = cur ^ 1;
      GLL(kG, &KB[nxt][wave * 512]);
      GLL(vG, &VB[nxt][wave * 512]);
      kG += (size_t)64 * HD; vG += 64;
    }
    const unsigned short* Kl = KB[cur];
    const unsigned short* Vt = VB[cur];

    // S^T = K Q^T per 16-key tile; exp2 + pack; concat pairs -> x32 A-frags
    bf16x8 apack[2][2];
    #pragma unroll
    for (int t = 0; t < 2; ++t) {
      const bf16x8 kf00 = *(const bf16x8*)&Kl[kRi[4 * t + 0]];
      const bf16x8 kf01 = *(const bf16x8*)&Kl[kRi[4 * t + 1]];
      const bf16x8 kf10 = *(const bf16x8*)&Kl[kRi[4 * t + 2]];
      const bf16x8 kf11 = *(const bf16x8*)&Kl[kRi[4 * t + 3]];
      #pragma unroll
      for (int s = 0; s < 2; ++s) {
        f32x4 sa = {0.f,0.f,0.f,0.f}, sb = {0.f,0.f,0.f,0.f};
        sa = __builtin_amdgcn_mfma_f32_16x16x32_bf16(kf00, aq[s][0], sa, 0, 0, 0);
        sa = __builtin_amdgcn_mfma_f32_16x16x32_bf16(kf01, aq[s][1], sa, 0, 0, 0);
        sb = __builtin_amdgcn_mfma_f32_16x16x32_bf16(kf10, aq[s][0], sb, 0, 0, 0);
        sb = __builtin_amdgcn_mfma_f32_16x16x32_bf16(kf11, aq[s][1], sb, 0, 0, 0);
        union { unsigned u[4]; bf16x8 v; } pk;
        pk.u[0] = pktr(__builtin_amdgcn_exp2f(sa[0]), __builtin_amdgcn_exp2f(sa[1]));
        pk.u[1] = pktr(__builtin_amdgcn_exp2f(sa[2]), __builtin_amdgcn_exp2f(sa[3]));
        pk.u[2] = pktr(__builtin_amdgcn_exp2f(sb[0]), __builtin_amdgcn_exp2f(sb[1]));
        pk.u[3] = pktr(__builtin_amdgcn_exp2f(sb[2]), __builtin_amdgcn_exp2f(sb[3]));
        apack[s][t] = pk.v;
      }
    }

    __builtin_amdgcn_s_setprio(1);   // favor the pure-MFMA cluster (T5)
    #pragma unroll
    for (int dt = 0; dt < 4; ++dt) {
      const bf16x8 vb0 = *(const bf16x8*)&Vt[kRi[2 * dt]];
      const bf16x8 vb1 = *(const bf16x8*)&Vt[kRi[2 * dt + 1]];
      #pragma unroll
      for (int s = 0; s < 2; ++s) {
        o[s][dt] = __builtin_amdgcn_mfma_f32_16x16x32_bf16(apack[s][0], vb0, o[s][dt], 0, 0, 0);
        o[s][dt] = __builtin_amdgcn_mfma_f32_16x16x32_bf16(apack[s][1], vb1, o[s][dt], 0, 0, 0);
      }
    }
    #pragma unroll
    for (int s = 0; s < 2; ++s) {
      lacc[s] = __builtin_amdgcn_mfma_f32_16x16x32_bf16(apack[s][0], bones8, lacc[s], 0, 0, 0);
      lacc[s] = __builtin_amdgcn_mfma_f32_16x16x32_bf16(apack[s][1], bones8, lacc[s], 0, 0, 0);
    }
    __builtin_amdgcn_s_setprio(0);
  }

  // epilogue: plain stores of partials (each element written exactly once)
  float* __restrict__ Od = (sp == 0) ? O : Opb + (size_t)(sp - 1) * S_LEN * HID;
  #pragma unroll
  for (int s = 0; s < 2; ++s) {
    #pragma unroll
    for (int dt = 0; dt < 4; ++dt) {
      #pragma unroll
      for (int r = 0; r < 4; ++r) {
        const int row = q0 + wave * 32 + s * 16 + 4 * g + r;
        Od[(size_t)row * HID + h * HD + dt * 16 + c] = o[s][dt][r];
      }
    }
  }
  if (c == 0) {
    #pragma unroll
    for (int s = 0; s < 2; ++s)
      #pragma unroll
      for (int r = 0; r < 4; ++r) {
        const int row = q0 + wave * 32 + s * 16 + 4 * g + r;
        Lp[((size_t)sp * NH + h) * S_LEN + row] = lacc[s][r];
      }
  }
}

// ---------------------------------------------------------------------------
// Kernel 3: merge the NSP KV-split partials and normalize by the softmax
// denominator. Pure-BW.
// ---------------------------------------------------------------------------
template<int NSP>
__global__ __launch_bounds__(256) void reduce_norm(float* __restrict__ O,
                                                   const float* __restrict__ Opb,
                                                   const float* __restrict__ Lp)
{
  const int i = blockIdx.x * 256 + threadIdx.x;
  float4 a = ((const float4*)O)[i];
  const int idx4 = i * 4;
  const int row = idx4 / HID;
  const int h   = (idx4 % HID) >> 6;
  float l = Lp[h * S_LEN + row];
  #pragma unroll
  for (int s = 1; s < NSP; ++s) {
    const float4 b = ((const float4*)(Opb + (size_t)(s - 1) * S_LEN * HID))[i];
    a.x += b.x; a.y += b.y; a.z += b.z; a.w += b.w;
    l += Lp[((size_t)s * NH + h) * S_LEN + row];
  }
  const float inv = 1.0f / l;
  a.x *= inv; a.y *= inv; a.z *= inv; a.w *= inv;
  ((float4*)O)[i] = a;
}

// ---------------------------------------------------------------------------
extern "C" void kernel_launch(void* const* d_in, const int* in_sizes, int n_in,
                              void* d_out, int out_size, void* d_ws, size_t ws_size,
                              hipStream_t stream) {
  const float* X  = (const float*)d_in[0];
  const float* Wq = (const float*)d_in[1];
  const float* bq = (const float*)d_in[2];
  const float* Wk = (const float*)d_in[3];
  const float* bk = (const float*)d_in[4];
  const float* Wv = (const float*)d_in[5];
  const float* bv = (const float*)d_in[6];

  unsigned short* Xb = (unsigned short*)d_ws;
  unsigned short* Wt = Xb + (size_t)S_LEN * HID;
  unsigned short* Qb = Wt + (size_t)3 * HID * HID;
  unsigned short* Kb = Qb + (size_t)NH * S_LEN * HD;
  unsigned short* Vb = Kb + (size_t)NH * S_LEN * HD;
  float* Opb = (float*)(Vb + (size_t)NH * S_LEN * HD);

  // bytes needed for NSP=4: bf16 bufs + 3 O-partials + 4*NH*S L-partials
  const size_t ush = (size_t)S_LEN * HID + (size_t)3 * HID * HID + (size_t)3 * NH * S_LEN * HD;
  const size_t need4 = ush * 2 + ((size_t)3 * S_LEN * HID + (size_t)4 * NH * S_LEN) * 4;
  const bool s4 = ws_size >= need4;

  float* Lp = Opb + (size_t)(s4 ? 3 : 1) * S_LEN * HID;
  float* O = (float*)d_out;

  prep<<<dim3(3504), 256, 0, stream>>>(X, Wq, Wk, Wv, Xb, Wt);
  qkv_proj<<<dim3(12, 16, 3), 512, 0, stream>>>(Xb, Wt, bq, bk, bv, Qb, Kb, Vb);
  if (s4) {
    attn<4><<<dim3(768), 512, 0, stream>>>(Qb, Kb, Vb, O, Opb, Lp);
    reduce_norm<4><<<dim3((S_LEN * HID / 4) / 256), 256, 0, stream>>>(O, Opb, Lp);
  } else {
    attn<2><<<dim3(384), 512, 0, stream>>>(Qb, Kb, Vb, O, Opb, Lp);
    reduce_norm<2><<<dim3((S_LEN * HID / 4) / 256), 256, 0, stream>>>(O, Opb, Lp);
  }
}